// Round 25
// baseline (120.959 us; speedup 1.0000x reference)
//
#include <hip/hip_runtime.h>
#include <math.h>

#define S_DIM 128
#define R_DIM 256
#define CM_DIM 256
#define CZ_DIM 128
#define C_DIM 32
#define H_DIM 8
#define HC_DIM 256
#define LN_EPS 1e-5f
#define ZPAD 132
#define HSZ 1048576  // S*R*C = per-head slab size (halves)
#define BIAS_SCALE 16384.0f
#define BIAS_INV (1.0f / 16384.0f)

typedef _Float16 half8 __attribute__((ext_vector_type(8)));
typedef _Float16 half4 __attribute__((ext_vector_type(4)));
typedef float f32x4 __attribute__((ext_vector_type(4)));
typedef short short4v __attribute__((ext_vector_type(4)));
typedef short short8v __attribute__((ext_vector_type(8)));

__device__ __forceinline__ float wave_sum(float v) {
#pragma unroll
    for (int off = 32; off > 0; off >>= 1) v += __shfl_down(v, off);
    return v;
}

// async global->LDS DMA, 16B per lane (dest = wave-uniform base + lane*16)
__device__ __forceinline__ void gload16(const _Float16* src, _Float16* dst) {
    __builtin_amdgcn_global_load_lds((const __attribute__((address_space(1))) void*)src,
                                     (__attribute__((address_space(3))) void*)dst, 16, 0, 0);
}

// K0: convert+retile weights: W[k][n] f32 -> W3[mat][kb][n][kk] fp16 (kb=k/32, kk=k%32)
__global__ __launch_bounds__(256) void convert_w_kernel(const float* __restrict__ Wq,
                                                        const float* __restrict__ Wk,
                                                        const float* __restrict__ Wv,
                                                        const float* __restrict__ Wg,
                                                        const float* __restrict__ Wo,
                                                        _Float16* __restrict__ w3) {
    int kb = blockIdx.x;   // 0..7
    int mat = blockIdx.y;  // 0..4
    const float* src = (mat == 0) ? Wq : (mat == 1) ? Wk : (mat == 2) ? Wv : (mat == 3) ? Wg : Wo;
    int n = threadIdx.x;
    _Float16 tmp[32];
#pragma unroll
    for (int kk = 0; kk < 32; kk++)
        tmp[kk] = (_Float16)src[(size_t)(kb * 32 + kk) * 256 + n];
    half8* dst = (half8*)(w3 + (size_t)mat * 65536 + (size_t)kb * 8192 + (size_t)n * 32);
#pragma unroll
    for (int i = 0; i < 4; i++) dst[i] = *(half8*)&tmp[i * 8];
}

// K0b: precompute u[h][c] = ln_z_w[c]*Wz[c][h] (padded rows ZPAD), U[h], B[h].
__global__ __launch_bounds__(64) void prep_wz_kernel(const float* __restrict__ w,
                                                     const float* __restrict__ b,
                                                     const float* __restrict__ Wz,
                                                     float* __restrict__ u_g,
                                                     float* __restrict__ UB) {
    int lane = threadIdx.x;
    float w0 = w[lane], w1 = w[lane + 64];
    float b0 = b[lane], b1 = b[lane + 64];
#pragma unroll
    for (int h = 0; h < H_DIM; h++) {
        float wz0 = Wz[lane * H_DIM + h], wz1 = Wz[(lane + 64) * H_DIM + h];
        float u0 = w0 * wz0, u1 = w1 * wz1;
        u_g[h * ZPAD + lane] = u0;
        u_g[h * ZPAD + lane + 64] = u1;
        float U = wave_sum(u0 + u1);
        float B = wave_sum(b0 * wz0 + b1 * wz1);
        if (lane == 0) { UB[h] = U; UB[8 + h] = B; }
    }
}

// K1: LayerNorm m -> fp16. One wave per row.
__global__ __launch_bounds__(64) void ln_m_kernel(const float* __restrict__ m,
                                                  const float* __restrict__ w,
                                                  const float* __restrict__ b,
                                                  _Float16* __restrict__ mn) {
    int row = blockIdx.x;
    int t = threadIdx.x;
    const float4* mrow = (const float4*)(m + (size_t)row * CM_DIM);
    float4 x = mrow[t];
    float s = x.x + x.y + x.z + x.w;
    float ss = x.x * x.x + x.y * x.y + x.z * x.z + x.w * x.w;
    s = wave_sum(s);
    ss = wave_sum(ss);
    s = __shfl(s, 0);
    ss = __shfl(ss, 0);
    float mean = s * (1.0f / CM_DIM);
    float var = ss * (1.0f / CM_DIM) - mean * mean;
    float rsig = rsqrtf(var + LN_EPS);
    float4 wv = ((const float4*)w)[t];
    float4 bv = ((const float4*)b)[t];
    half4 o;
    o[0] = (_Float16)((x.x - mean) * rsig * wv.x + bv.x);
    o[1] = (_Float16)((x.y - mean) * rsig * wv.y + bv.y);
    o[2] = (_Float16)((x.z - mean) * rsig * wv.z + bv.z);
    o[3] = (_Float16)((x.w - mean) * rsig * wv.w + bv.w);
    *(half4*)(mn + (size_t)row * CM_DIM + t * 4) = o;
}

// K2: LN(z) folded into bias dot: bias_h = rsig*(A_h - mu*U_h) + B_h.
// Output bias int16 (scale 2^14), layout [h][q][k].
__global__ __launch_bounds__(256) void ln_z_bias_kernel(const float* __restrict__ z,
                                                        const float* __restrict__ u_g,
                                                        const float* __restrict__ UB,
                                                        short* __restrict__ bias_i) {
    __shared__ __align__(16) float zt[64 * ZPAD];
    __shared__ __align__(16) float ut[8 * ZPAD];
    __shared__ float UBs[16];
    int tid = threadIdx.x;
    int row0 = blockIdx.x * 64;  // flattened (q*256+k)
    for (int i = tid; i < 8 * ZPAD; i += 256) ut[i] = u_g[i];
    if (tid < 16) UBs[tid] = UB[tid];
    const float4* zsrc = (const float4*)(z + (size_t)row0 * CZ_DIM);
#pragma unroll
    for (int i = 0; i < 8; i++) {
        int idx = tid + i * 256;  // float4 index in 64x128 tile
        float4 v = zsrc[idx];
        int r = idx >> 5, c4 = (idx & 31) * 4;
        *(float4*)&zt[r * ZPAD + c4] = v;
    }
    __syncthreads();
    int r = tid >> 2, p = tid & 3;
    const float* zr = &zt[r * ZPAD];
    const float* u0p = &ut[p * ZPAD];
    const float* u1p = &ut[(p + 4) * ZPAD];
    float s = 0.f, ss = 0.f, a0 = 0.f, a1 = 0.f;
#pragma unroll
    for (int c = 0; c < CZ_DIM; c += 4) {
        float4 x = *(const float4*)&zr[c];
        float4 uu0 = *(const float4*)&u0p[c];
        float4 uu1 = *(const float4*)&u1p[c];
        s += x.x + x.y + x.z + x.w;
        ss += x.x * x.x + x.y * x.y + x.z * x.z + x.w * x.w;
        a0 += x.x * uu0.x + x.y * uu0.y + x.z * uu0.z + x.w * uu0.w;
        a1 += x.x * uu1.x + x.y * uu1.y + x.z * uu1.z + x.w * uu1.w;
    }
    float mu = s * (1.0f / CZ_DIM);
    float var = ss * (1.0f / CZ_DIM) - mu * mu;
    float rsig = rsqrtf(var + LN_EPS);
    int row = row0 + r;
    float b0v = rsig * (a0 - mu * UBs[p]) + UBs[8 + p];
    float b1v = rsig * (a1 - mu * UBs[4 + p]) + UBs[12 + p];
    int i0 = (int)rintf(b0v * BIAS_SCALE);
    int i1 = (int)rintf(b1v * BIAS_SCALE);
    i0 = i0 > 32767 ? 32767 : (i0 < -32768 ? -32768 : i0);
    i1 = i1 > 32767 ? 32767 : (i1 < -32768 ? -32768 : i1);
    bias_i[(size_t)p * 65536 + row] = (short)i0;
    bias_i[(size_t)(p + 4) * 65536 + row] = (short)i1;
}

// K3: projections with BOTH operands in LDS. A staged once (swizzled DMA,
// conflict-free reads); B double-buffered (T3 issue-early/drain-late).
// Inner loop = ds_read + MFMA only -> nothing for the compiler to sink.
// LDS 72.25KB -> 2 blocks/CU. Half-width Os epilogue (2 passes).
__global__ __launch_bounds__(256, 2) void proj_mfma_kernel(const _Float16* __restrict__ A,
                                                           const _Float16* __restrict__ w3,
                                                           const float* __restrict__ bg,
                                                           _Float16* __restrict__ qh,
                                                           _Float16* __restrict__ kh,
                                                           _Float16* __restrict__ vh,
                                                           _Float16* __restrict__ gh) {
    __shared__ _Float16 As[64 * 256];     // 32KB [row][chunk^=(row&7)]
    __shared__ _Float16 Bs[2][64 * 128];  // 32KB [col][chunk c ^= (col&7)]
    __shared__ _Float16 Os[64 * 66];      // 8.25KB half-width epilogue staging
    int m0 = blockIdx.x * 64;
    int col0 = blockIdx.y * 128;
    int tid = threadIdx.x, lane = tid & 63, wave = tid >> 6;
    int lrow = lane & 15, g = lane >> 4;
    int wr = wave >> 1, wc = wave & 1;
    const float qscale = 0.17677669529663687f;  // 32^-0.5

    // stage A swizzled once: LDS[row][c] = A[row][chunk c ^ (row&7)]
#pragma unroll
    for (int i = 0; i < 8; i++) {
        int j = tid + i * 256;
        int row = j >> 5;
        int c = (j & 31) ^ (row & 7);
        gload16(A + (size_t)(m0 + row) * 256 + c * 8, As + (size_t)j * 8);
    }

#define STAGE_B(T, BUF)                                                              \
    {                                                                                \
        int mat_ = (T) >> 2, kp_ = (T) & 3;                                          \
        _Float16* dst_ = &Bs[BUF][0];                                                \
        const _Float16* src_ = w3 + (size_t)mat_ * 65536 + (size_t)kp_ * 16384;      \
        _Pragma("unroll") for (int i_ = 0; i_ < 4; i_++) {                           \
            int j_ = tid + i_ * 256;                                                 \
            int n_ = j_ >> 3, cL_ = j_ & 7;                                          \
            int c_ = cL_ ^ (n_ & 7);                                                 \
            int kbL_ = c_ >> 2, q_ = c_ & 3;                                         \
            gload16(src_ + (size_t)kbL_ * 8192 + (size_t)(col0 + n_) * 32 + q_ * 8,  \
                    dst_ + (size_t)j_ * 8);                                          \
        }                                                                            \
    }

    STAGE_B(0, 0);
    STAGE_B(1, 1);
    __syncthreads();  // drains A + first two B tiles (exposed once)

    f32x4 acc[2][4];
    for (int t = 0; t < 16; t++) {
        int buf = t & 1;
        int mat = t >> 2, kp = t & 3;
        if (kp == 0) {
#pragma unroll
            for (int i = 0; i < 2; i++)
#pragma unroll
                for (int j = 0; j < 4; j++) acc[i][j] = (f32x4){0.f, 0.f, 0.f, 0.f};
        }
#pragma unroll
        for (int kbL = 0; kbL < 2; kbL++) {
            int kb = kp * 2 + kbL;
            half8 af[2], bf[4];
#pragma unroll
            for (int mf = 0; mf < 2; mf++) {
                int row = wr * 32 + mf * 16 + lrow;
                af[mf] = *(half8*)&As[row * 256 + (((kb * 4 + g) ^ (row & 7)) * 8)];
            }
#pragma unroll
            for (int nf = 0; nf < 4; nf++) {
                int col = wc * 64 + nf * 16 + lrow;
                int chunk = (kbL * 4 + g) ^ (col & 7);
                bf[nf] = *(half8*)&Bs[buf][(size_t)(col * 8 + chunk) * 8];
            }
#pragma unroll
            for (int mf = 0; mf < 2; mf++)
#pragma unroll
                for (int nf = 0; nf < 4; nf++)
                    acc[mf][nf] = __builtin_amdgcn_mfma_f32_16x16x32_f16(af[mf], bf[nf],
                                                                         acc[mf][nf], 0, 0, 0);
        }
        if (kp == 3) {
            // epilogue in 2 col-half passes (Os is 64x66)
#pragma unroll
            for (int hf2 = 0; hf2 < 2; hf2++) {
                __syncthreads();  // prior pass copy-out reads done / Bs reads done
                if (wc == hf2) {
#pragma unroll
                    for (int mf = 0; mf < 2; mf++)
#pragma unroll
                        for (int nf = 0; nf < 4; nf++)
#pragma unroll
                            for (int ri = 0; ri < 4; ri++) {
                                int srow = wr * 32 + mf * 16 + g * 4 + ri;
                                int scol = nf * 16 + lrow;  // 0..63 within half
                                float v = acc[mf][nf][ri];
                                if (mat == 0) v *= qscale;
                                if (mat == 3)
                                    v = 1.0f / (1.0f + __expf(-(v + bg[col0 + hf2 * 64 + scol])));
                                Os[srow * 66 + scol] = (_Float16)v;
                            }
                }
                __syncthreads();
                if (mat < 3) {
                    _Float16* Out = (mat == 0) ? qh : (mat == 1) ? kh : vh;
                    // 2 head slabs x 64 rows x 4 chunks = 512 chunks / 256 thr
#pragma unroll
                    for (int i = 0; i < 2; i++) {
                        int j = tid + i * 256;
                        int slab = j >> 8, jj = j & 255;
                        int row = jj >> 2, cOff = (jj & 3) * 8;
                        half8 v8 = *(half8*)&Os[row * 66 + slab * 32 + cOff];
                        *(half8*)(Out + (size_t)((col0 >> 5) + hf2 * 2 + slab) * HSZ +
                                  (size_t)(m0 + row) * 32 + cOff) = v8;
                    }
                } else {
                    // g row-major: 64 rows x 8 chunks = 512 chunks / 256 thr
#pragma unroll
                    for (int i = 0; i < 2; i++) {
                        int j = tid + i * 256;
                        int row = j >> 3, cOff = (j & 7) * 8;
                        half8 v8 = *(half8*)&Os[row * 66 + cOff];
                        *(half8*)(gh + (size_t)(m0 + row) * 256 + col0 + hf2 * 64 + cOff) = v8;
                    }
                }
            }
        }
        __syncthreads();  // frees Bs[buf]; drains in-flight DMA
        if (t + 2 < 16) STAGE_B(t + 2, buf);  // lands under next tile's compute
    }
#undef STAGE_B
}

// K4: bias-in-LDS flash attention, 1024 threads = TWO independent 8-wave groups.
// PV via K=16 MFMA: QK^T D-layout == 16x16x16 B-layout -> ZERO shuffles.
__global__ __launch_bounds__(1024, 1) void attn_mfma_kernel(const _Float16* __restrict__ qh,
                                                            const _Float16* __restrict__ kh,
                                                            const _Float16* __restrict__ vh,
                                                            const _Float16* __restrict__ gh,
                                                            const short* __restrict__ bias_i,
                                                            _Float16* __restrict__ oh) {
    __shared__ short bias_s[256][264];       // 135 KB
    __shared__ _Float16 K_s[2][64][40];      // 10 KB
    __shared__ _Float16 VT_s[2][32][68];     // 8.7 KB (stride 68 -> no conflicts)
    int h = blockIdx.x, sg = blockIdx.y;     // grid (8, 32)
    int tid = threadIdx.x;
    int grp = tid >> 9;                      // 0,1
    int t5 = tid & 511;
    int lane = tid & 63, wave = t5 >> 6;     // wave 0..7 within group
    int lrow = lane & 15, g = lane >> 4, lk8 = g * 8;
    int qw = wave * 32;

    const short* bsrc = bias_i + (size_t)h * 65536;
#pragma unroll
    for (int i = 0; i < 8; i++) {
        int e = (tid + i * 1024) * 8;
        short8v v = *(const short8v*)(bsrc + e);
        *(short8v*)&bias_s[e >> 8][e & 255] = v;
    }

    const _Float16* qbase = qh + (size_t)h * HSZ;
    const _Float16* kbase = kh + (size_t)h * HSZ;
    const _Float16* vbase = vh + (size_t)h * HSZ;
    _Float16* obase = oh + (size_t)h * HSZ;

    bool isK = (wave < 4);
    int key = (t5 & 255) >> 2, koff = (t5 & 3) * 8;  // group waves 0-3 stage K
    int vkey = t5 & 63, vc0 = ((t5 >> 6) & 3) * 8;   // group waves 4-7 stage V

    for (int si = 0; si < 2; si++) {
        int s = sg * 4 + grp * 2 + si;
        half8 qfr[2];
#pragma unroll
        for (int qf = 0; qf < 2; qf++)
            qfr[qf] = *(const half8*)(qbase + (size_t)(s * 256 + qw + qf * 16 + lrow) * 32 + lk8);

        f32x4 oaccT[2][2];
        float m_run[2], l_run[2];
#pragma unroll
        for (int qf = 0; qf < 2; qf++) {
            oaccT[qf][0] = (f32x4){0.f, 0.f, 0.f, 0.f};
            oaccT[qf][1] = (f32x4){0.f, 0.f, 0.f, 0.f};
            m_run[qf] = -1e30f;
            l_run[qf] = 0.f;
        }

        half8 stg;
        if (isK) stg = *(const half8*)(kbase + (size_t)(s * 256 + key) * 32 + koff);
        else     stg = *(const half8*)(vbase + (size_t)(s * 256 + vkey) * 32 + vc0);

        for (int kb = 0; kb < 4; kb++) {
            __syncthreads();  // (first pass also covers bias prologue)
            if (isK) {
                *(half8*)&K_s[grp][key][koff] = stg;
            } else {
#pragma unroll
                for (int j = 0; j < 8; j++) VT_s[grp][vc0 + j][vkey] = stg[j];
            }
            if (kb < 3) {
                int nk = (kb + 1) * 64;
                if (isK) stg = *(const half8*)(kbase + (size_t)(s * 256 + nk + key) * 32 + koff);
                else     stg = *(const half8*)(vbase + (size_t)(s * 256 + nk + vkey) * 32 + vc0);
            }
            __syncthreads();

            half8 kfr[4];
#pragma unroll
            for (int kf = 0; kf < 4; kf++) kfr[kf] = *(half8*)&K_s[grp][kf * 16 + lrow][lk8];

#pragma unroll
            for (int qf = 0; qf < 2; qf++) {
                f32x4 sf[4];
#pragma unroll
                for (int kf = 0; kf < 4; kf++) {
                    f32x4 zero = (f32x4){0.f, 0.f, 0.f, 0.f};
                    sf[kf] = __builtin_amdgcn_mfma_f32_16x16x32_f16(kfr[kf], qfr[qf], zero, 0, 0, 0);
                }
                int q = qw + qf * 16 + lrow;
#pragma unroll
                for (int kf = 0; kf < 4; kf++) {
                    short4v bh = *(short4v*)&bias_s[q][kb * 64 + kf * 16 + 4 * g];
#pragma unroll
                    for (int ri = 0; ri < 4; ri++) sf[kf][ri] += (float)bh[ri] * BIAS_INV;
                }
                float tm = -1e30f;
#pragma unroll
                for (int kf = 0; kf < 4; kf++)
#pragma unroll
                    for (int ri = 0; ri < 4; ri++) tm = fmaxf(tm, sf[kf][ri]);
                tm = fmaxf(tm, __shfl_xor(tm, 16));
                tm = fmaxf(tm, __shfl_xor(tm, 32));
                float nm = fmaxf(m_run[qf], tm);
                float sc = __expf(m_run[qf] - nm);
                m_run[qf] = nm;
                oaccT[qf][0] *= sc;
                oaccT[qf][1] *= sc;
                // exp + pack to half4 per kf (D-layout == 16x16x16 B-layout)
                float rs = 0.f;
                half4 pfr[4];
#pragma unroll
                for (int kf = 0; kf < 4; kf++)
#pragma unroll
                    for (int ri = 0; ri < 4; ri++) {
                        float pv = __expf(sf[kf][ri] - nm);
                        rs += pv;
                        pfr[kf][ri] = (_Float16)pv;
                    }
                rs += __shfl_xor(rs, 16);
                rs += __shfl_xor(rs, 32);
                l_run[qf] = l_run[qf] * sc + rs;
                // PV: direct K=16 MFMA, no cross-lane movement
#pragma unroll
                for (int kf = 0; kf < 4; kf++)
#pragma unroll
                    for (int cf = 0; cf < 2; cf++) {
                        half4 va = *(half4*)&VT_s[grp][cf * 16 + lrow][kf * 16 + 4 * g];
                        oaccT[qf][cf] = __builtin_amdgcn_mfma_f32_16x16x16f16(va, pfr[kf],
                                                                              oaccT[qf][cf], 0, 0, 0);
                    }
            }
        }
        // O write, g fused (f32 multiply before the single fp16 round)
#pragma unroll
        for (int qf = 0; qf < 2; qf++) {
            float inv = 1.0f / l_run[qf];
            int q = qw + qf * 16 + lrow;
#pragma unroll
            for (int cf = 0; cf < 2; cf++) {
                half4 gv4 = *(const half4*)(gh + (size_t)(s * 256 + q) * 256 + h * 32 + cf * 16 + 4 * g);
                half4 o4;
#pragma unroll
                for (int ri = 0; ri < 4; ri++)
                    o4[ri] = (_Float16)(oaccT[qf][cf][ri] * inv * (float)gv4[ri]);
                *(half4*)(obase + (size_t)(s * 256 + q) * 32 + cf * 16 + 4 * g) = o4;
            }
        }
    }
}

// K5: out = o_premul @ Wo + bo. REGISTER A + double-buffered B (T3 ordering).
__global__ __launch_bounds__(256, 4) void out_mfma_kernel(const _Float16* __restrict__ oh,
                                                          const _Float16* __restrict__ w3o,
                                                          const float* __restrict__ bo,
                                                          float* __restrict__ out) {
    __shared__ _Float16 Bs[2][64 * 128];
    int m0 = blockIdx.x * 64;
    int col0 = blockIdx.y * 128;
    int tid = threadIdx.x, lane = tid & 63, wave = tid >> 6;
    int lrow = lane & 15, g = lane >> 4;
    int wr = wave >> 1, wc = wave & 1;

    half8 afr[2][8];
#pragma unroll
    for (int mf = 0; mf < 2; mf++)
#pragma unroll
        for (int kb = 0; kb < 8; kb++)
            afr[mf][kb] = *(const half8*)(oh + (size_t)kb * HSZ +
                                          (size_t)(m0 + wr * 32 + mf * 16 + lrow) * 32 + g * 8);

#define STAGE_BO(T, BUF)                                                             \
    {                                                                                \
        int kp_ = (T);                                                               \
        _Float16* dst_ = &Bs[BUF][0];                                                \
        const _Float16* src_ = w3o + (size_t)kp_ * 16384;                            \
        _Pragma("unroll") for (int i_ = 0; i_ < 4; i_++) {                           \
            int j_ = tid + i_ * 256;                                                 \
            int n_ = j_ >> 3, cL_ = j_ & 7;                                          \
            int c_ = cL_ ^ (n_ & 7);                                                 \
            int kbL_ = c_ >> 2, q_ = c_ & 3;                                         \
            gload16(src_ + (size_t)kbL_ * 8192 + (size_t)(col0 + n_) * 32 + q_ * 8,  \
                    dst_ + (size_t)j_ * 8);                                          \
        }                                                                            \
    }

    STAGE_BO(0, 0);
    STAGE_BO(1, 1);
    __syncthreads();

    f32x4 acc[2][4];
#pragma unroll
    for (int i = 0; i < 2; i++)
#pragma unroll
        for (int j = 0; j < 4; j++) acc[i][j] = (f32x4){0.f, 0.f, 0.f, 0.f};

    for (int t = 0; t < 4; t++) {
        int buf = t & 1;
#pragma unroll
        for (int kbL = 0; kbL < 2; kbL++) {
            int kb = t * 2 + kbL;
            half8 bf[4];
#pragma unroll
            for (int nf = 0; nf < 4; nf++) {
                int col = wc * 64 + nf * 16 + lrow;
                int chunk = (kbL * 4 + g) ^ (col & 7);
                bf[nf] = *(half8*)&Bs[buf][(size_t)(col * 8 + chunk) * 8];
            }
#pragma unroll
            for (int mf = 0; mf < 2; mf++)
#pragma unroll
                for (int nf = 0; nf < 4; nf++)
                    acc[mf][nf] = __builtin_amdgcn_mfma_f32_16x16x32_f16(afr[mf][kb], bf[nf],
                                                                         acc[mf][nf], 0, 0, 0);
        }
        __syncthreads();
        if (t + 2 < 4) STAGE_BO(t + 2, buf);
    }
#undef STAGE_BO

#pragma unroll
    for (int mf = 0; mf < 2; mf++)
#pragma unroll
        for (int nf = 0; nf < 4; nf++)
#pragma unroll
            for (int ri = 0; ri < 4; ri++) {
                int row = m0 + wr * 32 + mf * 16 + g * 4 + ri;
                int col = col0 + wc * 64 + nf * 16 + lrow;
                out[(size_t)row * 256 + col] = acc[mf][nf][ri] + bo[col];
            }
}

extern "C" void kernel_launch(void* const* d_in, const int* in_sizes, int n_in,
                              void* d_out, int out_size, void* d_ws, size_t ws_size,
                              hipStream_t stream) {
    const float* m = (const float*)d_in[0];
    const float* z = (const float*)d_in[1];
    const float* ln_m_w = (const float*)d_in[2];
    const float* ln_m_b = (const float*)d_in[3];
    const float* ln_z_w = (const float*)d_in[4];
    const float* ln_z_b = (const float*)d_in[5];
    const float* Wz = (const float*)d_in[6];
    const float* Wq = (const float*)d_in[7];
    const float* Wk = (const float*)d_in[8];
    const float* Wv = (const float*)d_in[9];
    const float* Wg = (const float*)d_in[10];
    const float* bg = (const float*)d_in[11];
    const float* Wo = (const float*)d_in[12];
    const float* bo = (const float*)d_in[13];
    float* out = (float*)d_out;

    const size_t NE = (size_t)S_DIM * R_DIM * CM_DIM;  // 8388608
    _Float16* hb = (_Float16*)d_ws;
    _Float16* mn_h = hb;
    _Float16* qh = hb + NE;
    _Float16* kh = hb + 2 * NE;
    _Float16* vh = hb + 3 * NE;
    _Float16* gh = hb + 4 * NE;
    _Float16* oh = hb + 5 * NE;
    _Float16* w3 = hb + 6 * NE;                        // 5*65536 halves
    float* u_g = (float*)(hb + 6 * NE + 5 * 65536);    // 8*ZPAD f32
    float* UB = u_g + 8 * ZPAD;                        // 16 f32
    short* bias_i = (short*)(UB + 16);                 // H*R*R int16

    hipLaunchKernelGGL(convert_w_kernel, dim3(8, 5), dim3(256), 0, stream,
                       Wq, Wk, Wv, Wg, Wo, w3);
    hipLaunchKernelGGL(prep_wz_kernel, dim3(1), dim3(64), 0, stream,
                       ln_z_w, ln_z_b, Wz, u_g, UB);
    hipLaunchKernelGGL(ln_m_kernel, dim3(S_DIM * R_DIM), dim3(64), 0, stream,
                       m, ln_m_w, ln_m_b, mn_h);
    hipLaunchKernelGGL(ln_z_bias_kernel, dim3(1024), dim3(256), 0, stream,
                       z, u_g, UB, bias_i);
    hipLaunchKernelGGL(proj_mfma_kernel, dim3(512, 2), dim3(256), 0, stream,
                       mn_h, w3, bg, qh, kh, vh, gh);
    hipLaunchKernelGGL(attn_mfma_kernel, dim3(H_DIM, 32), dim3(1024), 0, stream,
                       qh, kh, vh, gh, bias_i, oh);
    hipLaunchKernelGGL(out_mfma_kernel, dim3(512, 2), dim3(256), 0, stream,
                       oh, w3 + 4 * 65536, bo, out);
}

// Round 26
// 116.130 us; speedup vs baseline: 1.0416x; 1.0416x over previous
//
#include <hip/hip_runtime.h>
#include <math.h>

#define S_DIM 128
#define R_DIM 256
#define CM_DIM 256
#define CZ_DIM 128
#define C_DIM 32
#define H_DIM 8
#define HC_DIM 256
#define LN_EPS 1e-5f
#define ZPAD 132
#define HSZ 1048576  // S*R*C = per-head slab size (halves)
#define BIAS_SCALE 16384.0f
#define BIAS_INV (1.0f / 16384.0f)

typedef _Float16 half8 __attribute__((ext_vector_type(8)));
typedef _Float16 half4 __attribute__((ext_vector_type(4)));
typedef float f32x4 __attribute__((ext_vector_type(4)));
typedef short short4v __attribute__((ext_vector_type(4)));
typedef short short8v __attribute__((ext_vector_type(8)));

__device__ __forceinline__ float wave_sum(float v) {
#pragma unroll
    for (int off = 32; off > 0; off >>= 1) v += __shfl_down(v, off);
    return v;
}

// async global->LDS DMA, 16B per lane (dest = wave-uniform base + lane*16)
__device__ __forceinline__ void gload16(const _Float16* src, _Float16* dst) {
    __builtin_amdgcn_global_load_lds((const __attribute__((address_space(1))) void*)src,
                                     (__attribute__((address_space(3))) void*)dst, 16, 0, 0);
}

// K0: convert+retile weights: W[k][n] f32 -> W3[mat][kb][n][kk] fp16 (kb=k/32, kk=k%32)
__global__ __launch_bounds__(256) void convert_w_kernel(const float* __restrict__ Wq,
                                                        const float* __restrict__ Wk,
                                                        const float* __restrict__ Wv,
                                                        const float* __restrict__ Wg,
                                                        const float* __restrict__ Wo,
                                                        _Float16* __restrict__ w3) {
    int kb = blockIdx.x;   // 0..7
    int mat = blockIdx.y;  // 0..4
    const float* src = (mat == 0) ? Wq : (mat == 1) ? Wk : (mat == 2) ? Wv : (mat == 3) ? Wg : Wo;
    int n = threadIdx.x;
    _Float16 tmp[32];
#pragma unroll
    for (int kk = 0; kk < 32; kk++)
        tmp[kk] = (_Float16)src[(size_t)(kb * 32 + kk) * 256 + n];
    half8* dst = (half8*)(w3 + (size_t)mat * 65536 + (size_t)kb * 8192 + (size_t)n * 32);
#pragma unroll
    for (int i = 0; i < 4; i++) dst[i] = *(half8*)&tmp[i * 8];
}

// K0b: precompute u[h][c] = ln_z_w[c]*Wz[c][h] (padded rows ZPAD), U[h], B[h].
__global__ __launch_bounds__(64) void prep_wz_kernel(const float* __restrict__ w,
                                                     const float* __restrict__ b,
                                                     const float* __restrict__ Wz,
                                                     float* __restrict__ u_g,
                                                     float* __restrict__ UB) {
    int lane = threadIdx.x;
    float w0 = w[lane], w1 = w[lane + 64];
    float b0 = b[lane], b1 = b[lane + 64];
#pragma unroll
    for (int h = 0; h < H_DIM; h++) {
        float wz0 = Wz[lane * H_DIM + h], wz1 = Wz[(lane + 64) * H_DIM + h];
        float u0 = w0 * wz0, u1 = w1 * wz1;
        u_g[h * ZPAD + lane] = u0;
        u_g[h * ZPAD + lane + 64] = u1;
        float U = wave_sum(u0 + u1);
        float B = wave_sum(b0 * wz0 + b1 * wz1);
        if (lane == 0) { UB[h] = U; UB[8 + h] = B; }
    }
}

// K1: LayerNorm m -> fp16. One wave per row.
__global__ __launch_bounds__(64) void ln_m_kernel(const float* __restrict__ m,
                                                  const float* __restrict__ w,
                                                  const float* __restrict__ b,
                                                  _Float16* __restrict__ mn) {
    int row = blockIdx.x;
    int t = threadIdx.x;
    const float4* mrow = (const float4*)(m + (size_t)row * CM_DIM);
    float4 x = mrow[t];
    float s = x.x + x.y + x.z + x.w;
    float ss = x.x * x.x + x.y * x.y + x.z * x.z + x.w * x.w;
    s = wave_sum(s);
    ss = wave_sum(ss);
    s = __shfl(s, 0);
    ss = __shfl(ss, 0);
    float mean = s * (1.0f / CM_DIM);
    float var = ss * (1.0f / CM_DIM) - mean * mean;
    float rsig = rsqrtf(var + LN_EPS);
    float4 wv = ((const float4*)w)[t];
    float4 bv = ((const float4*)b)[t];
    half4 o;
    o[0] = (_Float16)((x.x - mean) * rsig * wv.x + bv.x);
    o[1] = (_Float16)((x.y - mean) * rsig * wv.y + bv.y);
    o[2] = (_Float16)((x.z - mean) * rsig * wv.z + bv.z);
    o[3] = (_Float16)((x.w - mean) * rsig * wv.w + bv.w);
    *(half4*)(mn + (size_t)row * CM_DIM + t * 4) = o;
}

// K2: LN(z) folded into bias dot: bias_h = rsig*(A_h - mu*U_h) + B_h.
// Output bias int16 (scale 2^14), layout [h][q][k].
__global__ __launch_bounds__(256) void ln_z_bias_kernel(const float* __restrict__ z,
                                                        const float* __restrict__ u_g,
                                                        const float* __restrict__ UB,
                                                        short* __restrict__ bias_i) {
    __shared__ __align__(16) float zt[64 * ZPAD];
    __shared__ __align__(16) float ut[8 * ZPAD];
    __shared__ float UBs[16];
    int tid = threadIdx.x;
    int row0 = blockIdx.x * 64;  // flattened (q*256+k)
    for (int i = tid; i < 8 * ZPAD; i += 256) ut[i] = u_g[i];
    if (tid < 16) UBs[tid] = UB[tid];
    const float4* zsrc = (const float4*)(z + (size_t)row0 * CZ_DIM);
#pragma unroll
    for (int i = 0; i < 8; i++) {
        int idx = tid + i * 256;  // float4 index in 64x128 tile
        float4 v = zsrc[idx];
        int r = idx >> 5, c4 = (idx & 31) * 4;
        *(float4*)&zt[r * ZPAD + c4] = v;
    }
    __syncthreads();
    int r = tid >> 2, p = tid & 3;
    const float* zr = &zt[r * ZPAD];
    const float* u0p = &ut[p * ZPAD];
    const float* u1p = &ut[(p + 4) * ZPAD];
    float s = 0.f, ss = 0.f, a0 = 0.f, a1 = 0.f;
#pragma unroll
    for (int c = 0; c < CZ_DIM; c += 4) {
        float4 x = *(const float4*)&zr[c];
        float4 uu0 = *(const float4*)&u0p[c];
        float4 uu1 = *(const float4*)&u1p[c];
        s += x.x + x.y + x.z + x.w;
        ss += x.x * x.x + x.y * x.y + x.z * x.z + x.w * x.w;
        a0 += x.x * uu0.x + x.y * uu0.y + x.z * uu0.z + x.w * uu0.w;
        a1 += x.x * uu1.x + x.y * uu1.y + x.z * uu1.z + x.w * uu1.w;
    }
    float mu = s * (1.0f / CZ_DIM);
    float var = ss * (1.0f / CZ_DIM) - mu * mu;
    float rsig = rsqrtf(var + LN_EPS);
    int row = row0 + r;
    float b0v = rsig * (a0 - mu * UBs[p]) + UBs[8 + p];
    float b1v = rsig * (a1 - mu * UBs[4 + p]) + UBs[12 + p];
    int i0 = (int)rintf(b0v * BIAS_SCALE);
    int i1 = (int)rintf(b1v * BIAS_SCALE);
    i0 = i0 > 32767 ? 32767 : (i0 < -32768 ? -32768 : i0);
    i1 = i1 > 32767 ? 32767 : (i1 < -32768 ? -32768 : i1);
    bias_i[(size_t)p * 65536 + row] = (short)i0;
    bias_i[(size_t)(p + 4) * 65536 + row] = (short)i1;
}

// K3: projections with REGISTER A + double-buffered B (issue-early, drain-late).
__global__ __launch_bounds__(256, 3) void proj_mfma_kernel(const _Float16* __restrict__ A,
                                                           const _Float16* __restrict__ w3,
                                                           const float* __restrict__ bg,
                                                           _Float16* __restrict__ qh,
                                                           _Float16* __restrict__ kh,
                                                           _Float16* __restrict__ vh,
                                                           _Float16* __restrict__ gh) {
    __shared__ _Float16 Bs[2][64 * 128];  // 2 x 16KB: [col][chunk c ^= (col&7)]
    __shared__ _Float16 Os[64 * 132];     // 16.5KB epilogue staging
    int m0 = blockIdx.x * 64;
    int col0 = blockIdx.y * 128;
    int tid = threadIdx.x, lane = tid & 63, wave = tid >> 6;
    int lrow = lane & 15, g = lane >> 4;
    int wr = wave >> 1, wc = wave & 1;
    const float qscale = 0.17677669529663687f;  // 32^-0.5

    half8 afr[2][8];
#pragma unroll
    for (int mf = 0; mf < 2; mf++)
#pragma unroll
        for (int kb = 0; kb < 8; kb++)
            afr[mf][kb] = *(const half8*)(A + (size_t)(m0 + wr * 32 + mf * 16 + lrow) * 256 +
                                          kb * 32 + g * 8);

#define STAGE_B(T, BUF)                                                              \
    {                                                                                \
        int mat_ = (T) >> 2, kp_ = (T) & 3;                                          \
        _Float16* dst_ = &Bs[BUF][0];                                                \
        const _Float16* src_ = w3 + (size_t)mat_ * 65536 + (size_t)kp_ * 16384;      \
        _Pragma("unroll") for (int i_ = 0; i_ < 4; i_++) {                           \
            int j_ = tid + i_ * 256;                                                 \
            int n_ = j_ >> 3, cL_ = j_ & 7;                                          \
            int c_ = cL_ ^ (n_ & 7);                                                 \
            int kbL_ = c_ >> 2, q_ = c_ & 3;                                         \
            gload16(src_ + (size_t)kbL_ * 8192 + (size_t)(col0 + n_) * 32 + q_ * 8,  \
                    dst_ + (size_t)j_ * 8);                                          \
        }                                                                            \
    }

    STAGE_B(0, 0);
    STAGE_B(1, 1);
    __syncthreads();

    f32x4 acc[2][4];
    for (int t = 0; t < 16; t++) {
        int buf = t & 1;
        int mat = t >> 2, kp = t & 3;
        if (kp == 0) {
#pragma unroll
            for (int i = 0; i < 2; i++)
#pragma unroll
                for (int j = 0; j < 4; j++) acc[i][j] = (f32x4){0.f, 0.f, 0.f, 0.f};
        }
#pragma unroll
        for (int kbL = 0; kbL < 2; kbL++) {
            int kb = kp * 2 + kbL;
            half8 bf[4];
#pragma unroll
            for (int nf = 0; nf < 4; nf++) {
                int col = wc * 64 + nf * 16 + lrow;
                int chunk = (kbL * 4 + g) ^ (col & 7);
                bf[nf] = *(half8*)&Bs[buf][(size_t)(col * 8 + chunk) * 8];
            }
#pragma unroll
            for (int mf = 0; mf < 2; mf++)
#pragma unroll
                for (int nf = 0; nf < 4; nf++)
                    acc[mf][nf] = __builtin_amdgcn_mfma_f32_16x16x32_f16(afr[mf][kb], bf[nf],
                                                                         acc[mf][nf], 0, 0, 0);
        }
        if (kp == 3) {
#pragma unroll
            for (int mf = 0; mf < 2; mf++)
#pragma unroll
                for (int nf = 0; nf < 4; nf++)
#pragma unroll
                    for (int ri = 0; ri < 4; ri++) {
                        int srow = wr * 32 + mf * 16 + g * 4 + ri;
                        int scol = wc * 64 + nf * 16 + lrow;
                        float v = acc[mf][nf][ri];
                        if (mat == 0) v *= qscale;
                        if (mat == 3) v = 1.0f / (1.0f + __expf(-(v + bg[col0 + scol])));
                        Os[srow * 132 + scol] = (_Float16)v;
                    }
            __syncthreads();
            if (mat < 3) {
                _Float16* Out = (mat == 0) ? qh : (mat == 1) ? kh : vh;
#pragma unroll
                for (int j = 0; j < 4; j++) {
                    int hh = (col0 >> 5) + j;
                    int row = tid >> 2, cOff = (tid & 3) * 8;
                    half8 v8 = *(half8*)&Os[row * 132 + j * 32 + cOff];
                    *(half8*)(Out + (size_t)hh * HSZ + (size_t)(m0 + row) * 32 + cOff) = v8;
                }
            } else {
#pragma unroll
                for (int i = 0; i < 4; i++) {
                    int c2 = tid + i * 256;
                    int row = c2 >> 4, cOff = (c2 & 15) * 8;
                    half8 v8 = *(half8*)&Os[row * 132 + cOff];
                    *(half8*)(gh + (size_t)(m0 + row) * 256 + col0 + cOff) = v8;
                }
            }
        }
        __syncthreads();
        if (t + 2 < 16) STAGE_B(t + 2, buf);
    }
#undef STAGE_B
}

// K4: bias-in-LDS flash attention, 1024 threads = TWO independent 8-wave groups.
// PV via K=16 MFMA: QK^T D-layout == 16x16x16 B-layout -> ZERO shuffles.
__global__ __launch_bounds__(1024, 1) void attn_mfma_kernel(const _Float16* __restrict__ qh,
                                                            const _Float16* __restrict__ kh,
                                                            const _Float16* __restrict__ vh,
                                                            const _Float16* __restrict__ gh,
                                                            const short* __restrict__ bias_i,
                                                            _Float16* __restrict__ oh) {
    __shared__ short bias_s[256][264];       // 135 KB
    __shared__ _Float16 K_s[2][64][40];      // 10 KB
    __shared__ _Float16 VT_s[2][32][68];     // 8.7 KB (stride 68 -> no conflicts)
    int h = blockIdx.x, sg = blockIdx.y;     // grid (8, 32)
    int tid = threadIdx.x;
    int grp = tid >> 9;                      // 0,1
    int t5 = tid & 511;
    int lane = tid & 63, wave = t5 >> 6;     // wave 0..7 within group
    int lrow = lane & 15, g = lane >> 4, lk8 = g * 8;
    int qw = wave * 32;

    const short* bsrc = bias_i + (size_t)h * 65536;
#pragma unroll
    for (int i = 0; i < 8; i++) {
        int e = (tid + i * 1024) * 8;
        short8v v = *(const short8v*)(bsrc + e);
        *(short8v*)&bias_s[e >> 8][e & 255] = v;
    }

    const _Float16* qbase = qh + (size_t)h * HSZ;
    const _Float16* kbase = kh + (size_t)h * HSZ;
    const _Float16* vbase = vh + (size_t)h * HSZ;
    _Float16* obase = oh + (size_t)h * HSZ;

    bool isK = (wave < 4);
    int key = (t5 & 255) >> 2, koff = (t5 & 3) * 8;  // group waves 0-3 stage K
    int vkey = t5 & 63, vc0 = ((t5 >> 6) & 3) * 8;   // group waves 4-7 stage V

    for (int si = 0; si < 2; si++) {
        int s = sg * 4 + grp * 2 + si;
        half8 qfr[2];
#pragma unroll
        for (int qf = 0; qf < 2; qf++)
            qfr[qf] = *(const half8*)(qbase + (size_t)(s * 256 + qw + qf * 16 + lrow) * 32 + lk8);

        f32x4 oaccT[2][2];
        float m_run[2], l_run[2];
#pragma unroll
        for (int qf = 0; qf < 2; qf++) {
            oaccT[qf][0] = (f32x4){0.f, 0.f, 0.f, 0.f};
            oaccT[qf][1] = (f32x4){0.f, 0.f, 0.f, 0.f};
            m_run[qf] = -1e30f;
            l_run[qf] = 0.f;
        }

        half8 stg;
        if (isK) stg = *(const half8*)(kbase + (size_t)(s * 256 + key) * 32 + koff);
        else     stg = *(const half8*)(vbase + (size_t)(s * 256 + vkey) * 32 + vc0);

        for (int kb = 0; kb < 4; kb++) {
            __syncthreads();  // (first pass also covers bias prologue)
            if (isK) {
                *(half8*)&K_s[grp][key][koff] = stg;
            } else {
#pragma unroll
                for (int j = 0; j < 8; j++) VT_s[grp][vc0 + j][vkey] = stg[j];
            }
            if (kb < 3) {
                int nk = (kb + 1) * 64;
                if (isK) stg = *(const half8*)(kbase + (size_t)(s * 256 + nk + key) * 32 + koff);
                else     stg = *(const half8*)(vbase + (size_t)(s * 256 + nk + vkey) * 32 + vc0);
            }
            __syncthreads();

            half8 kfr[4];
#pragma unroll
            for (int kf = 0; kf < 4; kf++) kfr[kf] = *(half8*)&K_s[grp][kf * 16 + lrow][lk8];

#pragma unroll
            for (int qf = 0; qf < 2; qf++) {
                f32x4 sf[4];
#pragma unroll
                for (int kf = 0; kf < 4; kf++) {
                    f32x4 zero = (f32x4){0.f, 0.f, 0.f, 0.f};
                    sf[kf] = __builtin_amdgcn_mfma_f32_16x16x32_f16(kfr[kf], qfr[qf], zero, 0, 0, 0);
                }
                int q = qw + qf * 16 + lrow;
#pragma unroll
                for (int kf = 0; kf < 4; kf++) {
                    short4v bh = *(short4v*)&bias_s[q][kb * 64 + kf * 16 + 4 * g];
#pragma unroll
                    for (int ri = 0; ri < 4; ri++) sf[kf][ri] += (float)bh[ri] * BIAS_INV;
                }
                float tm = -1e30f;
#pragma unroll
                for (int kf = 0; kf < 4; kf++)
#pragma unroll
                    for (int ri = 0; ri < 4; ri++) tm = fmaxf(tm, sf[kf][ri]);
                tm = fmaxf(tm, __shfl_xor(tm, 16));
                tm = fmaxf(tm, __shfl_xor(tm, 32));
                float nm = fmaxf(m_run[qf], tm);
                float sc = __expf(m_run[qf] - nm);
                m_run[qf] = nm;
                oaccT[qf][0] *= sc;
                oaccT[qf][1] *= sc;
                // exp + pack to half4 per kf (D-layout == 16x16x16 B-layout)
                float rs = 0.f;
                half4 pfr[4];
#pragma unroll
                for (int kf = 0; kf < 4; kf++)
#pragma unroll
                    for (int ri = 0; ri < 4; ri++) {
                        float pv = __expf(sf[kf][ri] - nm);
                        rs += pv;
                        pfr[kf][ri] = (_Float16)pv;
                    }
                rs += __shfl_xor(rs, 16);
                rs += __shfl_xor(rs, 32);
                l_run[qf] = l_run[qf] * sc + rs;
                // PV: direct K=16 MFMA, no cross-lane movement
#pragma unroll
                for (int kf = 0; kf < 4; kf++)
#pragma unroll
                    for (int cf = 0; cf < 2; cf++) {
                        half4 va = *(half4*)&VT_s[grp][cf * 16 + lrow][kf * 16 + 4 * g];
                        oaccT[qf][cf] = __builtin_amdgcn_mfma_f32_16x16x16f16(va, pfr[kf],
                                                                              oaccT[qf][cf], 0, 0, 0);
                    }
            }
        }
        // O write, g fused (f32 multiply before the single fp16 round)
#pragma unroll
        for (int qf = 0; qf < 2; qf++) {
            float inv = 1.0f / l_run[qf];
            int q = qw + qf * 16 + lrow;
#pragma unroll
            for (int cf = 0; cf < 2; cf++) {
                half4 gv4 = *(const half4*)(gh + (size_t)(s * 256 + q) * 256 + h * 32 + cf * 16 + 4 * g);
                half4 o4;
#pragma unroll
                for (int ri = 0; ri < 4; ri++)
                    o4[ri] = (_Float16)(oaccT[qf][cf][ri] * inv * (float)gv4[ri]);
                *(half4*)(obase + (size_t)(s * 256 + q) * 32 + cf * 16 + 4 * g) = o4;
            }
        }
    }
}

// K5: out = o_premul @ Wo + bo. REGISTER A + double-buffered B (T3 ordering).
__global__ __launch_bounds__(256, 4) void out_mfma_kernel(const _Float16* __restrict__ oh,
                                                          const _Float16* __restrict__ w3o,
                                                          const float* __restrict__ bo,
                                                          float* __restrict__ out) {
    __shared__ _Float16 Bs[2][64 * 128];
    int m0 = blockIdx.x * 64;
    int col0 = blockIdx.y * 128;
    int tid = threadIdx.x, lane = tid & 63, wave = tid >> 6;
    int lrow = lane & 15, g = lane >> 4;
    int wr = wave >> 1, wc = wave & 1;

    half8 afr[2][8];
#pragma unroll
    for (int mf = 0; mf < 2; mf++)
#pragma unroll
        for (int kb = 0; kb < 8; kb++)
            afr[mf][kb] = *(const half8*)(oh + (size_t)kb * HSZ +
                                          (size_t)(m0 + wr * 32 + mf * 16 + lrow) * 32 + g * 8);

#define STAGE_BO(T, BUF)                                                             \
    {                                                                                \
        int kp_ = (T);                                                               \
        _Float16* dst_ = &Bs[BUF][0];                                                \
        const _Float16* src_ = w3o + (size_t)kp_ * 16384;                            \
        _Pragma("unroll") for (int i_ = 0; i_ < 4; i_++) {                           \
            int j_ = tid + i_ * 256;                                                 \
            int n_ = j_ >> 3, cL_ = j_ & 7;                                          \
            int c_ = cL_ ^ (n_ & 7);                                                 \
            int kbL_ = c_ >> 2, q_ = c_ & 3;                                         \
            gload16(src_ + (size_t)kbL_ * 8192 + (size_t)(col0 + n_) * 32 + q_ * 8,  \
                    dst_ + (size_t)j_ * 8);                                          \
        }                                                                            \
    }

    STAGE_BO(0, 0);
    STAGE_BO(1, 1);
    __syncthreads();

    f32x4 acc[2][4];
#pragma unroll
    for (int i = 0; i < 2; i++)
#pragma unroll
        for (int j = 0; j < 4; j++) acc[i][j] = (f32x4){0.f, 0.f, 0.f, 0.f};

    for (int t = 0; t < 4; t++) {
        int buf = t & 1;
#pragma unroll
        for (int kbL = 0; kbL < 2; kbL++) {
            int kb = t * 2 + kbL;
            half8 bf[4];
#pragma unroll
            for (int nf = 0; nf < 4; nf++) {
                int col = wc * 64 + nf * 16 + lrow;
                int chunk = (kbL * 4 + g) ^ (col & 7);
                bf[nf] = *(half8*)&Bs[buf][(size_t)(col * 8 + chunk) * 8];
            }
#pragma unroll
            for (int mf = 0; mf < 2; mf++)
#pragma unroll
                for (int nf = 0; nf < 4; nf++)
                    acc[mf][nf] = __builtin_amdgcn_mfma_f32_16x16x32_f16(afr[mf][kb], bf[nf],
                                                                         acc[mf][nf], 0, 0, 0);
        }
        __syncthreads();
        if (t + 2 < 4) STAGE_BO(t + 2, buf);
    }
#undef STAGE_BO

#pragma unroll
    for (int mf = 0; mf < 2; mf++)
#pragma unroll
        for (int nf = 0; nf < 4; nf++)
#pragma unroll
            for (int ri = 0; ri < 4; ri++) {
                int row = m0 + wr * 32 + mf * 16 + g * 4 + ri;
                int col = col0 + wc * 64 + nf * 16 + lrow;
                out[(size_t)row * 256 + col] = acc[mf][nf][ri] + bo[col];
            }
}

extern "C" void kernel_launch(void* const* d_in, const int* in_sizes, int n_in,
                              void* d_out, int out_size, void* d_ws, size_t ws_size,
                              hipStream_t stream) {
    const float* m = (const float*)d_in[0];
    const float* z = (const float*)d_in[1];
    const float* ln_m_w = (const float*)d_in[2];
    const float* ln_m_b = (const float*)d_in[3];
    const float* ln_z_w = (const float*)d_in[4];
    const float* ln_z_b = (const float*)d_in[5];
    const float* Wz = (const float*)d_in[6];
    const float* Wq = (const float*)d_in[7];
    const float* Wk = (const float*)d_in[8];
    const float* Wv = (const float*)d_in[9];
    const float* Wg = (const float*)d_in[10];
    const float* bg = (const float*)d_in[11];
    const float* Wo = (const float*)d_in[12];
    const float* bo = (const float*)d_in[13];
    float* out = (float*)d_out;

    const size_t NE = (size_t)S_DIM * R_DIM * CM_DIM;  // 8388608
    _Float16* hb = (_Float16*)d_ws;
    _Float16* mn_h = hb;
    _Float16* qh = hb + NE;
    _Float16* kh = hb + 2 * NE;
    _Float16* vh = hb + 3 * NE;
    _Float16* gh = hb + 4 * NE;
    _Float16* oh = hb + 5 * NE;
    _Float16* w3 = hb + 6 * NE;                        // 5*65536 halves
    float* u_g = (float*)(hb + 6 * NE + 5 * 65536);    // 8*ZPAD f32
    float* UB = u_g + 8 * ZPAD;                        // 16 f32
    short* bias_i = (short*)(UB + 16);                 // H*R*R int16

    hipLaunchKernelGGL(convert_w_kernel, dim3(8, 5), dim3(256), 0, stream,
                       Wq, Wk, Wv, Wg, Wo, w3);
    hipLaunchKernelGGL(prep_wz_kernel, dim3(1), dim3(64), 0, stream,
                       ln_z_w, ln_z_b, Wz, u_g, UB);
    hipLaunchKernelGGL(ln_m_kernel, dim3(S_DIM * R_DIM), dim3(64), 0, stream,
                       m, ln_m_w, ln_m_b, mn_h);
    hipLaunchKernelGGL(ln_z_bias_kernel, dim3(1024), dim3(256), 0, stream,
                       z, u_g, UB, bias_i);
    hipLaunchKernelGGL(proj_mfma_kernel, dim3(512, 2), dim3(256), 0, stream,
                       mn_h, w3, bg, qh, kh, vh, gh);
    hipLaunchKernelGGL(attn_mfma_kernel, dim3(H_DIM, 32), dim3(1024), 0, stream,
                       qh, kh, vh, gh, bias_i, oh);
    hipLaunchKernelGGL(out_mfma_kernel, dim3(512, 2), dim3(256), 0, stream,
                       oh, w3 + 4 * 65536, bo, out);
}

// Round 27
// 114.966 us; speedup vs baseline: 1.0521x; 1.0101x over previous
//
#include <hip/hip_runtime.h>
#include <math.h>

#define S_DIM 128
#define R_DIM 256
#define CM_DIM 256
#define CZ_DIM 128
#define C_DIM 32
#define H_DIM 8
#define HC_DIM 256
#define LN_EPS 1e-5f
#define ZPAD 132
#define HSZ 1048576  // S*R*C = per-head slab size (halves)
#define BIAS_SCALE 16384.0f
#define BIAS_INV (1.0f / 16384.0f)

typedef _Float16 half8 __attribute__((ext_vector_type(8)));
typedef _Float16 half4 __attribute__((ext_vector_type(4)));
typedef float f32x4 __attribute__((ext_vector_type(4)));
typedef short short4v __attribute__((ext_vector_type(4)));
typedef short short8v __attribute__((ext_vector_type(8)));

__device__ __forceinline__ float wave_sum(float v) {
#pragma unroll
    for (int off = 32; off > 0; off >>= 1) v += __shfl_down(v, off);
    return v;
}

// async global->LDS DMA, 16B per lane (dest = wave-uniform base + lane*16)
__device__ __forceinline__ void gload16(const _Float16* src, _Float16* dst) {
    __builtin_amdgcn_global_load_lds((const __attribute__((address_space(1))) void*)src,
                                     (__attribute__((address_space(3))) void*)dst, 16, 0, 0);
}

// K0: convert+retile weights: W[k][n] f32 -> W3[mat][kb][n][kk] fp16 (kb=k/32, kk=k%32)
__global__ __launch_bounds__(256) void convert_w_kernel(const float* __restrict__ Wq,
                                                        const float* __restrict__ Wk,
                                                        const float* __restrict__ Wv,
                                                        const float* __restrict__ Wg,
                                                        const float* __restrict__ Wo,
                                                        _Float16* __restrict__ w3) {
    int kb = blockIdx.x;   // 0..7
    int mat = blockIdx.y;  // 0..4
    const float* src = (mat == 0) ? Wq : (mat == 1) ? Wk : (mat == 2) ? Wv : (mat == 3) ? Wg : Wo;
    int n = threadIdx.x;
    _Float16 tmp[32];
#pragma unroll
    for (int kk = 0; kk < 32; kk++)
        tmp[kk] = (_Float16)src[(size_t)(kb * 32 + kk) * 256 + n];
    half8* dst = (half8*)(w3 + (size_t)mat * 65536 + (size_t)kb * 8192 + (size_t)n * 32);
#pragma unroll
    for (int i = 0; i < 4; i++) dst[i] = *(half8*)&tmp[i * 8];
}

// K0b: precompute u[h][c] = ln_z_w[c]*Wz[c][h] (padded rows ZPAD), U[h], B[h].
__global__ __launch_bounds__(64) void prep_wz_kernel(const float* __restrict__ w,
                                                     const float* __restrict__ b,
                                                     const float* __restrict__ Wz,
                                                     float* __restrict__ u_g,
                                                     float* __restrict__ UB) {
    int lane = threadIdx.x;
    float w0 = w[lane], w1 = w[lane + 64];
    float b0 = b[lane], b1 = b[lane + 64];
#pragma unroll
    for (int h = 0; h < H_DIM; h++) {
        float wz0 = Wz[lane * H_DIM + h], wz1 = Wz[(lane + 64) * H_DIM + h];
        float u0 = w0 * wz0, u1 = w1 * wz1;
        u_g[h * ZPAD + lane] = u0;
        u_g[h * ZPAD + lane + 64] = u1;
        float U = wave_sum(u0 + u1);
        float B = wave_sum(b0 * wz0 + b1 * wz1);
        if (lane == 0) { UB[h] = U; UB[8 + h] = B; }
    }
}

// K1: LayerNorm m -> fp16. One wave per row.
__global__ __launch_bounds__(64) void ln_m_kernel(const float* __restrict__ m,
                                                  const float* __restrict__ w,
                                                  const float* __restrict__ b,
                                                  _Float16* __restrict__ mn) {
    int row = blockIdx.x;
    int t = threadIdx.x;
    const float4* mrow = (const float4*)(m + (size_t)row * CM_DIM);
    float4 x = mrow[t];
    float s = x.x + x.y + x.z + x.w;
    float ss = x.x * x.x + x.y * x.y + x.z * x.z + x.w * x.w;
    s = wave_sum(s);
    ss = wave_sum(ss);
    s = __shfl(s, 0);
    ss = __shfl(ss, 0);
    float mean = s * (1.0f / CM_DIM);
    float var = ss * (1.0f / CM_DIM) - mean * mean;
    float rsig = rsqrtf(var + LN_EPS);
    float4 wv = ((const float4*)w)[t];
    float4 bv = ((const float4*)b)[t];
    half4 o;
    o[0] = (_Float16)((x.x - mean) * rsig * wv.x + bv.x);
    o[1] = (_Float16)((x.y - mean) * rsig * wv.y + bv.y);
    o[2] = (_Float16)((x.z - mean) * rsig * wv.z + bv.z);
    o[3] = (_Float16)((x.w - mean) * rsig * wv.w + bv.w);
    *(half4*)(mn + (size_t)row * CM_DIM + t * 4) = o;
}

// K2: LN(z) folded into bias dot: bias_h = rsig*(A_h - mu*U_h) + B_h.
// Output bias int16 (scale 2^14), layout [h][q][k].
__global__ __launch_bounds__(256) void ln_z_bias_kernel(const float* __restrict__ z,
                                                        const float* __restrict__ u_g,
                                                        const float* __restrict__ UB,
                                                        short* __restrict__ bias_i) {
    __shared__ __align__(16) float zt[64 * ZPAD];
    __shared__ __align__(16) float ut[8 * ZPAD];
    __shared__ float UBs[16];
    int tid = threadIdx.x;
    int row0 = blockIdx.x * 64;  // flattened (q*256+k)
    for (int i = tid; i < 8 * ZPAD; i += 256) ut[i] = u_g[i];
    if (tid < 16) UBs[tid] = UB[tid];
    const float4* zsrc = (const float4*)(z + (size_t)row0 * CZ_DIM);
#pragma unroll
    for (int i = 0; i < 8; i++) {
        int idx = tid + i * 256;  // float4 index in 64x128 tile
        float4 v = zsrc[idx];
        int r = idx >> 5, c4 = (idx & 31) * 4;
        *(float4*)&zt[r * ZPAD + c4] = v;
    }
    __syncthreads();
    int r = tid >> 2, p = tid & 3;
    const float* zr = &zt[r * ZPAD];
    const float* u0p = &ut[p * ZPAD];
    const float* u1p = &ut[(p + 4) * ZPAD];
    float s = 0.f, ss = 0.f, a0 = 0.f, a1 = 0.f;
#pragma unroll
    for (int c = 0; c < CZ_DIM; c += 4) {
        float4 x = *(const float4*)&zr[c];
        float4 uu0 = *(const float4*)&u0p[c];
        float4 uu1 = *(const float4*)&u1p[c];
        s += x.x + x.y + x.z + x.w;
        ss += x.x * x.x + x.y * x.y + x.z * x.z + x.w * x.w;
        a0 += x.x * uu0.x + x.y * uu0.y + x.z * uu0.z + x.w * uu0.w;
        a1 += x.x * uu1.x + x.y * uu1.y + x.z * uu1.z + x.w * uu1.w;
    }
    float mu = s * (1.0f / CZ_DIM);
    float var = ss * (1.0f / CZ_DIM) - mu * mu;
    float rsig = rsqrtf(var + LN_EPS);
    int row = row0 + r;
    float b0v = rsig * (a0 - mu * UBs[p]) + UBs[8 + p];
    float b1v = rsig * (a1 - mu * UBs[4 + p]) + UBs[12 + p];
    int i0 = (int)rintf(b0v * BIAS_SCALE);
    int i1 = (int)rintf(b1v * BIAS_SCALE);
    i0 = i0 > 32767 ? 32767 : (i0 < -32768 ? -32768 : i0);
    i1 = i1 > 32767 ? 32767 : (i1 < -32768 ? -32768 : i1);
    bias_i[(size_t)p * 65536 + row] = (short)i0;
    bias_i[(size_t)(p + 4) * 65536 + row] = (short)i1;
}

// K3: projections, 512 thr / 8 waves, wave tile 16x64. afr[8] = 32 VGPRs ->
// genuinely RESIDENT register A. B double-buffered in LDS (T3 ordering).
__global__ __launch_bounds__(512, 2) void proj_mfma_kernel(const _Float16* __restrict__ A,
                                                           const _Float16* __restrict__ w3,
                                                           const float* __restrict__ bg,
                                                           _Float16* __restrict__ qh,
                                                           _Float16* __restrict__ kh,
                                                           _Float16* __restrict__ vh,
                                                           _Float16* __restrict__ gh) {
    __shared__ _Float16 Bs[2][64 * 128];  // 2 x 16KB: [col][chunk c ^= (col&7)]
    __shared__ _Float16 Os[64 * 132];     // 16.5KB epilogue staging
    int m0 = blockIdx.x * 64;
    int col0 = blockIdx.y * 128;
    int tid = threadIdx.x, lane = tid & 63, wave = tid >> 6;  // 8 waves
    int lrow = lane & 15, g = lane >> 4;
    int wr = wave >> 1, wc = wave & 1;  // wr 0..3 (16-row slab), wc 0..1
    const float qscale = 0.17677669529663687f;  // 32^-0.5

    // A fragments: 8 half8 = 32 VGPRs -> fits residently
    half8 afr[8];
#pragma unroll
    for (int kb = 0; kb < 8; kb++)
        afr[kb] = *(const half8*)(A + (size_t)(m0 + wr * 16 + lrow) * 256 + kb * 32 + g * 8);

#define STAGE_B(T, BUF)                                                              \
    {                                                                                \
        int mat_ = (T) >> 2, kp_ = (T) & 3;                                          \
        _Float16* dst_ = &Bs[BUF][0];                                                \
        const _Float16* src_ = w3 + (size_t)mat_ * 65536 + (size_t)kp_ * 16384;      \
        _Pragma("unroll") for (int i_ = 0; i_ < 2; i_++) {                           \
            int j_ = tid + i_ * 512;                                                 \
            int n_ = j_ >> 3, cL_ = j_ & 7;                                          \
            int c_ = cL_ ^ (n_ & 7);                                                 \
            int kbL_ = c_ >> 2, q_ = c_ & 3;                                         \
            gload16(src_ + (size_t)kbL_ * 8192 + (size_t)(col0 + n_) * 32 + q_ * 8,  \
                    dst_ + (size_t)j_ * 8);                                          \
        }                                                                            \
    }

    STAGE_B(0, 0);
    STAGE_B(1, 1);
    __syncthreads();

    f32x4 acc[4];
    for (int t = 0; t < 16; t++) {
        int buf = t & 1;
        int mat = t >> 2, kp = t & 3;
        if (kp == 0) {
#pragma unroll
            for (int j = 0; j < 4; j++) acc[j] = (f32x4){0.f, 0.f, 0.f, 0.f};
        }
#pragma unroll
        for (int kbL = 0; kbL < 2; kbL++) {
            int kb = kp * 2 + kbL;
            half8 bf[4];
#pragma unroll
            for (int nf = 0; nf < 4; nf++) {
                int col = wc * 64 + nf * 16 + lrow;
                int chunk = (kbL * 4 + g) ^ (col & 7);
                bf[nf] = *(half8*)&Bs[buf][(size_t)(col * 8 + chunk) * 8];
            }
#pragma unroll
            for (int nf = 0; nf < 4; nf++)
                acc[nf] = __builtin_amdgcn_mfma_f32_16x16x32_f16(afr[kb], bf[nf], acc[nf], 0, 0, 0);
        }
        if (kp == 3) {
#pragma unroll
            for (int nf = 0; nf < 4; nf++)
#pragma unroll
                for (int ri = 0; ri < 4; ri++) {
                    int srow = wr * 16 + g * 4 + ri;
                    int scol = wc * 64 + nf * 16 + lrow;
                    float v = acc[nf][ri];
                    if (mat == 0) v *= qscale;
                    if (mat == 3) v = 1.0f / (1.0f + __expf(-(v + bg[col0 + scol])));
                    Os[srow * 132 + scol] = (_Float16)v;
                }
            __syncthreads();
            if (mat < 3) {
                _Float16* Out = (mat == 0) ? qh : (mat == 1) ? kh : vh;
                // 4 head slabs x 64 rows x 4 chunks = 1024 chunks / 512 thr
#pragma unroll
                for (int i = 0; i < 2; i++) {
                    int j = tid + i * 512;
                    int slab = j >> 8, jj = j & 255;
                    int row = jj >> 2, cOff = (jj & 3) * 8;
                    half8 v8 = *(half8*)&Os[row * 132 + slab * 32 + cOff];
                    *(half8*)(Out + (size_t)((col0 >> 5) + slab) * HSZ +
                              (size_t)(m0 + row) * 32 + cOff) = v8;
                }
            } else {
                // g row-major: 64 rows x 16 chunks = 1024 chunks / 512 thr
#pragma unroll
                for (int i = 0; i < 2; i++) {
                    int j = tid + i * 512;
                    int row = j >> 4, cOff = (j & 15) * 8;
                    half8 v8 = *(half8*)&Os[row * 132 + cOff];
                    *(half8*)(gh + (size_t)(m0 + row) * 256 + col0 + cOff) = v8;
                }
            }
        }
        __syncthreads();
        if (t + 2 < 16) STAGE_B(t + 2, buf);
    }
#undef STAGE_B
}

// K4: bias-in-LDS flash attention, 1024 threads = TWO independent 8-wave groups.
// PV via K=16 MFMA: QK^T D-layout == 16x16x16 B-layout -> ZERO shuffles.
__global__ __launch_bounds__(1024, 1) void attn_mfma_kernel(const _Float16* __restrict__ qh,
                                                            const _Float16* __restrict__ kh,
                                                            const _Float16* __restrict__ vh,
                                                            const _Float16* __restrict__ gh,
                                                            const short* __restrict__ bias_i,
                                                            _Float16* __restrict__ oh) {
    __shared__ short bias_s[256][264];       // 135 KB
    __shared__ _Float16 K_s[2][64][40];      // 10 KB
    __shared__ _Float16 VT_s[2][32][68];     // 8.7 KB (stride 68 -> no conflicts)
    int h = blockIdx.x, sg = blockIdx.y;     // grid (8, 32)
    int tid = threadIdx.x;
    int grp = tid >> 9;                      // 0,1
    int t5 = tid & 511;
    int lane = tid & 63, wave = t5 >> 6;     // wave 0..7 within group
    int lrow = lane & 15, g = lane >> 4, lk8 = g * 8;
    int qw = wave * 32;

    const short* bsrc = bias_i + (size_t)h * 65536;
#pragma unroll
    for (int i = 0; i < 8; i++) {
        int e = (tid + i * 1024) * 8;
        short8v v = *(const short8v*)(bsrc + e);
        *(short8v*)&bias_s[e >> 8][e & 255] = v;
    }

    const _Float16* qbase = qh + (size_t)h * HSZ;
    const _Float16* kbase = kh + (size_t)h * HSZ;
    const _Float16* vbase = vh + (size_t)h * HSZ;
    _Float16* obase = oh + (size_t)h * HSZ;

    bool isK = (wave < 4);
    int key = (t5 & 255) >> 2, koff = (t5 & 3) * 8;  // group waves 0-3 stage K
    int vkey = t5 & 63, vc0 = ((t5 >> 6) & 3) * 8;   // group waves 4-7 stage V

    for (int si = 0; si < 2; si++) {
        int s = sg * 4 + grp * 2 + si;
        half8 qfr[2];
#pragma unroll
        for (int qf = 0; qf < 2; qf++)
            qfr[qf] = *(const half8*)(qbase + (size_t)(s * 256 + qw + qf * 16 + lrow) * 32 + lk8);

        f32x4 oaccT[2][2];
        float m_run[2], l_run[2];
#pragma unroll
        for (int qf = 0; qf < 2; qf++) {
            oaccT[qf][0] = (f32x4){0.f, 0.f, 0.f, 0.f};
            oaccT[qf][1] = (f32x4){0.f, 0.f, 0.f, 0.f};
            m_run[qf] = -1e30f;
            l_run[qf] = 0.f;
        }

        half8 stg;
        if (isK) stg = *(const half8*)(kbase + (size_t)(s * 256 + key) * 32 + koff);
        else     stg = *(const half8*)(vbase + (size_t)(s * 256 + vkey) * 32 + vc0);

        for (int kb = 0; kb < 4; kb++) {
            __syncthreads();  // (first pass also covers bias prologue)
            if (isK) {
                *(half8*)&K_s[grp][key][koff] = stg;
            } else {
#pragma unroll
                for (int j = 0; j < 8; j++) VT_s[grp][vc0 + j][vkey] = stg[j];
            }
            if (kb < 3) {
                int nk = (kb + 1) * 64;
                if (isK) stg = *(const half8*)(kbase + (size_t)(s * 256 + nk + key) * 32 + koff);
                else     stg = *(const half8*)(vbase + (size_t)(s * 256 + nk + vkey) * 32 + vc0);
            }
            __syncthreads();

            half8 kfr[4];
#pragma unroll
            for (int kf = 0; kf < 4; kf++) kfr[kf] = *(half8*)&K_s[grp][kf * 16 + lrow][lk8];

#pragma unroll
            for (int qf = 0; qf < 2; qf++) {
                f32x4 sf[4];
#pragma unroll
                for (int kf = 0; kf < 4; kf++) {
                    f32x4 zero = (f32x4){0.f, 0.f, 0.f, 0.f};
                    sf[kf] = __builtin_amdgcn_mfma_f32_16x16x32_f16(kfr[kf], qfr[qf], zero, 0, 0, 0);
                }
                int q = qw + qf * 16 + lrow;
#pragma unroll
                for (int kf = 0; kf < 4; kf++) {
                    short4v bh = *(short4v*)&bias_s[q][kb * 64 + kf * 16 + 4 * g];
#pragma unroll
                    for (int ri = 0; ri < 4; ri++) sf[kf][ri] += (float)bh[ri] * BIAS_INV;
                }
                float tm = -1e30f;
#pragma unroll
                for (int kf = 0; kf < 4; kf++)
#pragma unroll
                    for (int ri = 0; ri < 4; ri++) tm = fmaxf(tm, sf[kf][ri]);
                tm = fmaxf(tm, __shfl_xor(tm, 16));
                tm = fmaxf(tm, __shfl_xor(tm, 32));
                float nm = fmaxf(m_run[qf], tm);
                float sc = __expf(m_run[qf] - nm);
                m_run[qf] = nm;
                oaccT[qf][0] *= sc;
                oaccT[qf][1] *= sc;
                // exp + pack to half4 per kf (D-layout == 16x16x16 B-layout)
                float rs = 0.f;
                half4 pfr[4];
#pragma unroll
                for (int kf = 0; kf < 4; kf++)
#pragma unroll
                    for (int ri = 0; ri < 4; ri++) {
                        float pv = __expf(sf[kf][ri] - nm);
                        rs += pv;
                        pfr[kf][ri] = (_Float16)pv;
                    }
                rs += __shfl_xor(rs, 16);
                rs += __shfl_xor(rs, 32);
                l_run[qf] = l_run[qf] * sc + rs;
                // PV: direct K=16 MFMA, no cross-lane movement
#pragma unroll
                for (int kf = 0; kf < 4; kf++)
#pragma unroll
                    for (int cf = 0; cf < 2; cf++) {
                        half4 va = *(half4*)&VT_s[grp][cf * 16 + lrow][kf * 16 + 4 * g];
                        oaccT[qf][cf] = __builtin_amdgcn_mfma_f32_16x16x16f16(va, pfr[kf],
                                                                              oaccT[qf][cf], 0, 0, 0);
                    }
            }
        }
        // O write, g fused (f32 multiply before the single fp16 round)
#pragma unroll
        for (int qf = 0; qf < 2; qf++) {
            float inv = 1.0f / l_run[qf];
            int q = qw + qf * 16 + lrow;
#pragma unroll
            for (int cf = 0; cf < 2; cf++) {
                half4 gv4 = *(const half4*)(gh + (size_t)(s * 256 + q) * 256 + h * 32 + cf * 16 + 4 * g);
                half4 o4;
#pragma unroll
                for (int ri = 0; ri < 4; ri++)
                    o4[ri] = (_Float16)(oaccT[qf][cf][ri] * inv * (float)gv4[ri]);
                *(half4*)(obase + (size_t)(s * 256 + q) * 32 + cf * 16 + 4 * g) = o4;
            }
        }
    }
}

// K5: out = o_premul @ Wo + bo. REGISTER A + double-buffered B (T3 ordering).
__global__ __launch_bounds__(256, 4) void out_mfma_kernel(const _Float16* __restrict__ oh,
                                                          const _Float16* __restrict__ w3o,
                                                          const float* __restrict__ bo,
                                                          float* __restrict__ out) {
    __shared__ _Float16 Bs[2][64 * 128];
    int m0 = blockIdx.x * 64;
    int col0 = blockIdx.y * 128;
    int tid = threadIdx.x, lane = tid & 63, wave = tid >> 6;
    int lrow = lane & 15, g = lane >> 4;
    int wr = wave >> 1, wc = wave & 1;

    half8 afr[2][8];
#pragma unroll
    for (int mf = 0; mf < 2; mf++)
#pragma unroll
        for (int kb = 0; kb < 8; kb++)
            afr[mf][kb] = *(const half8*)(oh + (size_t)kb * HSZ +
                                          (size_t)(m0 + wr * 32 + mf * 16 + lrow) * 32 + g * 8);

#define STAGE_BO(T, BUF)                                                             \
    {                                                                                \
        int kp_ = (T);                                                               \
        _Float16* dst_ = &Bs[BUF][0];                                                \
        const _Float16* src_ = w3o + (size_t)kp_ * 16384;                            \
        _Pragma("unroll") for (int i_ = 0; i_ < 4; i_++) {                           \
            int j_ = tid + i_ * 256;                                                 \
            int n_ = j_ >> 3, cL_ = j_ & 7;                                          \
            int c_ = cL_ ^ (n_ & 7);                                                 \
            int kbL_ = c_ >> 2, q_ = c_ & 3;                                         \
            gload16(src_ + (size_t)kbL_ * 8192 + (size_t)(col0 + n_) * 32 + q_ * 8,  \
                    dst_ + (size_t)j_ * 8);                                          \
        }                                                                            \
    }

    STAGE_BO(0, 0);
    STAGE_BO(1, 1);
    __syncthreads();

    f32x4 acc[2][4];
#pragma unroll
    for (int i = 0; i < 2; i++)
#pragma unroll
        for (int j = 0; j < 4; j++) acc[i][j] = (f32x4){0.f, 0.f, 0.f, 0.f};

    for (int t = 0; t < 4; t++) {
        int buf = t & 1;
#pragma unroll
        for (int kbL = 0; kbL < 2; kbL++) {
            int kb = t * 2 + kbL;
            half8 bf[4];
#pragma unroll
            for (int nf = 0; nf < 4; nf++) {
                int col = wc * 64 + nf * 16 + lrow;
                int chunk = (kbL * 4 + g) ^ (col & 7);
                bf[nf] = *(half8*)&Bs[buf][(size_t)(col * 8 + chunk) * 8];
            }
#pragma unroll
            for (int mf = 0; mf < 2; mf++)
#pragma unroll
                for (int nf = 0; nf < 4; nf++)
                    acc[mf][nf] = __builtin_amdgcn_mfma_f32_16x16x32_f16(afr[mf][kb], bf[nf],
                                                                         acc[mf][nf], 0, 0, 0);
        }
        __syncthreads();
        if (t + 2 < 4) STAGE_BO(t + 2, buf);
    }
#undef STAGE_BO

#pragma unroll
    for (int mf = 0; mf < 2; mf++)
#pragma unroll
        for (int nf = 0; nf < 4; nf++)
#pragma unroll
            for (int ri = 0; ri < 4; ri++) {
                int row = m0 + wr * 32 + mf * 16 + g * 4 + ri;
                int col = col0 + wc * 64 + nf * 16 + lrow;
                out[(size_t)row * 256 + col] = acc[mf][nf][ri] + bo[col];
            }
}

extern "C" void kernel_launch(void* const* d_in, const int* in_sizes, int n_in,
                              void* d_out, int out_size, void* d_ws, size_t ws_size,
                              hipStream_t stream) {
    const float* m = (const float*)d_in[0];
    const float* z = (const float*)d_in[1];
    const float* ln_m_w = (const float*)d_in[2];
    const float* ln_m_b = (const float*)d_in[3];
    const float* ln_z_w = (const float*)d_in[4];
    const float* ln_z_b = (const float*)d_in[5];
    const float* Wz = (const float*)d_in[6];
    const float* Wq = (const float*)d_in[7];
    const float* Wk = (const float*)d_in[8];
    const float* Wv = (const float*)d_in[9];
    const float* Wg = (const float*)d_in[10];
    const float* bg = (const float*)d_in[11];
    const float* Wo = (const float*)d_in[12];
    const float* bo = (const float*)d_in[13];
    float* out = (float*)d_out;

    const size_t NE = (size_t)S_DIM * R_DIM * CM_DIM;  // 8388608
    _Float16* hb = (_Float16*)d_ws;
    _Float16* mn_h = hb;
    _Float16* qh = hb + NE;
    _Float16* kh = hb + 2 * NE;
    _Float16* vh = hb + 3 * NE;
    _Float16* gh = hb + 4 * NE;
    _Float16* oh = hb + 5 * NE;
    _Float16* w3 = hb + 6 * NE;                        // 5*65536 halves
    float* u_g = (float*)(hb + 6 * NE + 5 * 65536);    // 8*ZPAD f32
    float* UB = u_g + 8 * ZPAD;                        // 16 f32
    short* bias_i = (short*)(UB + 16);                 // H*R*R int16

    hipLaunchKernelGGL(convert_w_kernel, dim3(8, 5), dim3(256), 0, stream,
                       Wq, Wk, Wv, Wg, Wo, w3);
    hipLaunchKernelGGL(prep_wz_kernel, dim3(1), dim3(64), 0, stream,
                       ln_z_w, ln_z_b, Wz, u_g, UB);
    hipLaunchKernelGGL(ln_m_kernel, dim3(S_DIM * R_DIM), dim3(64), 0, stream,
                       m, ln_m_w, ln_m_b, mn_h);
    hipLaunchKernelGGL(ln_z_bias_kernel, dim3(1024), dim3(256), 0, stream,
                       z, u_g, UB, bias_i);
    hipLaunchKernelGGL(proj_mfma_kernel, dim3(512, 2), dim3(512), 0, stream,
                       mn_h, w3, bg, qh, kh, vh, gh);
    hipLaunchKernelGGL(attn_mfma_kernel, dim3(H_DIM, 32), dim3(1024), 0, stream,
                       qh, kh, vh, gh, bias_i, oh);
    hipLaunchKernelGGL(out_mfma_kernel, dim3(512, 2), dim3(256), 0, stream,
                       oh, w3 + 4 * 65536, bo, out);
}